// Round 13
// baseline (219.153 us; speedup 1.0000x reference)
//
#include <hip/hip_runtime.h>
#include <hip/hip_bf16.h>
#include <math.h>

#define N_CLS 16384
#define DDIM  128
#define LOG2E 1.4426950408889634f

#if __has_builtin(__builtin_amdgcn_exp2f)
#define EXP2(x) __builtin_amdgcn_exp2f(x)
#else
#define EXP2(x) exp2f(x)
#endif

typedef __attribute__((ext_vector_type(8))) short short8;   // 8 bf16 (4 VGPRs)
typedef __attribute__((ext_vector_type(4)))  float f32x4;
typedef __attribute__((ext_vector_type(16))) float f32x16;  // 32x32 MFMA accumulator

__device__ __forceinline__ unsigned short f2bf(float f) {
    __hip_bfloat16 h = __float2bfloat16(f);
    return *(unsigned short*)&h;
}

// ---------------------------------------------------------------------------
// 32x32x16 fragment layout (harness-verified r1/r2/r5/r8):
//   element (rr, k) of a 32-row tile, K=128 in 8 kc chunks:
//     lane = ((k>>3)&1)*32 + (rr&31), j = k&7
//     short offset = tile*4096 + kc*512 + lane*8 + j     (tile = 8 KB)
//
// prep v4 (r8): one thread per (pair i, k-slot sl), branch-free, coalesced.
// (Note: total-minus-fused ~64 us is constant across 4 different prep
// versions -> dominated by harness overhead; prep is not the lever.)
// ---------------------------------------------------------------------------
__global__ __launch_bounds__(256)
void prep_kernel(const float* __restrict__ x,
                 const int* __restrict__ aidx,
                 float* __restrict__ ap,
                 unsigned short* __restrict__ Afrag,
                 unsigned short* __restrict__ Bfrag,
                 float* __restrict__ out) {
    const int u  = blockIdx.x * 256 + threadIdx.x;  // unit 0..262143
    const int i  = u >> 4;                          // pair 0..16383
    const int sl = u & 15;                          // k-slot (8 floats each)
    const int k0 = sl * 8;

    const float* pa = x + (2L * i) * DDIM + k0;
    float fa[8], fb[8];
    *(float4*)&fa[0] = *(const float4*)(pa);
    *(float4*)&fa[4] = *(const float4*)(pa + 4);
    *(float4*)&fb[0] = *(const float4*)(pa + DDIM);
    *(float4*)&fb[4] = *(const float4*)(pa + DDIM + 4);
    const bool sel = (aidx[i] != 0);                // anchor = sel ? x[2i+1] : x[2i]

    short8 A, B;
    float d = 0.0f;
    #pragma unroll
    for (int j = 0; j < 8; ++j) {
        const float av = sel ? fb[j] : fa[j];
        A[j] = (short)f2bf(av * LOG2E);             // exp2 domain
        B[j] = (short)f2bf(fb[j]);                  // negative = x[2i+1]
        d += fa[j] * fb[j];                         // ap dot (symmetric)
    }
    const long dst = (long)(i >> 5) * 4096 + (sl >> 1) * 512 +
                     ((sl & 1) * 32 + (i & 31)) * 8;
    *(short8*)(Afrag + dst) = A;
    *(short8*)(Bfrag + dst) = B;

    d += __shfl_xor(d, 1, 64);
    d += __shfl_xor(d, 2, 64);
    d += __shfl_xor(d, 4, 64);
    d += __shfl_xor(d, 8, 64);
    if (sl == 0) ap[i] = d;
    if (u == 0) out[0] = 0.0f;
}

// ---------------------------------------------------------------------------
// fused v7: producer/consumer WAVE SPECIALIZATION (m114 verbatim).
// Falsified levers: intra-wave pipelining (r5), occupancy (r8), stagger
// (r11). All structures land 73-77 us with MfmaUtil~40 + VALUBusy~35 and
// strictly sequential pipes. m114 (HW-measured): an MFMA-only wave and a
// VALU-only wave co-run at full rate. So build exactly that:
//   block = 4 waves, 128 rows x 2048-col octant. 2 P-waves: LDS B-read +
//   MFMA only (2 row-tiles each = 2 indep 8-deep chains; R=2 B-reuse).
//   2 C-waves: read acc from LDS, exp2, accumulate, diagonal mask.
//   Handoff: 32x32 f32 acc via LDS (4 KB/tile; [g*1KB + lane*16B] b128
//   layout = conflict-free; C lane l inherits P lane l's C/D row map).
//   Single acc buffer + 2 barriers/step:
//     phaseX: P mfma(t) || C exp(t-1); bar1; phaseY: P acc->LDS + all-wave
//     staged B writes; bar2.
//   ROLE MUST ALTERNATE PER CO-RESIDENT BLOCK: waves map to SIMDs by index,
//   so role=(w>>1)^((bid>>8)&1) (co-resident bids differ in bit 8) else all
//   P-waves land on 2 SIMDs and halve matrix throughput.
// LDS 32 KB (16 B-dbuf + 16 acc) -> 4 blocks/CU. P regs ~122 -> (256,4).
// Spill signature: WRITE_SIZE >> 512 KB. Race signature: passed=false.
// ---------------------------------------------------------------------------
__global__ __launch_bounds__(256, 4)
void fused_kernel(const unsigned short* __restrict__ Afrag,
                  const unsigned short* __restrict__ Bfrag,
                  float* __restrict__ partial) {
    __shared__ __align__(16) unsigned short bs[2][4096];   // 16 KB B double-buffer
    __shared__ __align__(16) float accb[4][1024];          // 16 KB acc handoff
    const int tid  = threadIdx.x;
    const int lane = tid & 63;
    const int w    = tid >> 6;                 // wave 0..3
    const int l31  = lane & 31;
    const int hi   = lane >> 5;
    const int oct  = blockIdx.x & 7;           // XCD-aligned column octant
    const int rg   = blockIdx.x >> 3;          // row-group 0..127 (128 rows)
    const int rbit = (blockIdx.x >> 8) & 1;    // role-alternation bit
    const bool isP = (((w >> 1) ^ rbit) & 1) == 0;
    const int pair = w & 1;                    // which row-tile pair (0 or 1)
    const int gRow0 = rg * 4 + pair * 2;       // row-tiles this wave-pair owns
    const int gRow1 = gRow0 + 1;
    const int wchunk = w * 1024;               // staging chunk (shorts)

    const unsigned short* bbase = Bfrag + (long)oct * (64L * 4096);

    // diagonal col-tiles (wave-uniform; sentinel outside 0..63)
    int ctd0 = gRow0 - oct * 64;
    int ctd1 = gRow1 - oct * 64;
    if (ctd0 < 0 || ctd0 >= 64) ctd0 = -1000;
    if (ctd1 < 0 || ctd1 >= 64) ctd1 = -1000;

    // P state: A fragments for two row-tiles (64 VGPRs) + two accumulators
    short8 af0[8], af1[8];
    if (isP) {
        const unsigned short* a0 = Afrag + (long)gRow0 * 4096 + lane * 8;
        const unsigned short* a1 = Afrag + (long)gRow1 * 4096 + lane * 8;
        #pragma unroll
        for (int kc = 0; kc < 8; ++kc) {
            af0[kc] = *(const short8*)(a0 + kc * 512);
            af1[kc] = *(const short8*)(a1 + kc * 512);
        }
    }
    f32x16 acc0, acc1;

    // C state: running sums for two row-tiles
    float rs0[16], rs1[16];
    #pragma unroll
    for (int q = 0; q < 16; ++q) { rs0[q] = 0.0f; rs1[q] = 0.0f; }

    const float* ab0 = accb[pair * 2];
    const float* ab1 = accb[pair * 2 + 1];

    auto consume = [&](int ct) {
        #pragma unroll
        for (int g = 0; g < 4; ++g) {
            f32x4 v0 = *(const f32x4*)(ab0 + g * 256 + lane * 4);
            f32x4 v1 = *(const f32x4*)(ab1 + g * 256 + lane * 4);
            #pragma unroll
            for (int j = 0; j < 4; ++j) {
                const int row = j + 8 * g + 4 * hi;    // C/D row map
                float e0 = EXP2(v0[j]);
                float e1 = EXP2(v1[j]);
                if (ct == ctd0 && l31 == row) e0 = 0.0f;
                if (ct == ctd1 && l31 == row) e1 = 0.0f;
                rs0[g * 4 + j] += e0;
                rs1[g * 4 + j] += e1;
            }
        }
    };

    // prologue: all waves stage tile 0 into bs[0]
    {
        short8 s0 = *(const short8*)(bbase + wchunk + lane * 8);
        short8 s1 = *(const short8*)(bbase + wchunk + 512 + lane * 8);
        *(short8*)(&bs[0][wchunk + lane * 8]) = s0;
        *(short8*)(&bs[0][wchunk + 512 + lane * 8]) = s1;
    }
    __syncthreads();

    for (int t = 0; t < 64; ++t) {
        const int cur = t & 1;
        const long ntile = (t < 63) ? (long)(t + 1) : 63L;  // 63 reloads itself
        // staging loads issued early by ALL waves (latency hides under phase X)
        short8 n0 = *(const short8*)(bbase + ntile * 4096 + wchunk + lane * 8);
        short8 n1 = *(const short8*)(bbase + ntile * 4096 + wchunk + 512 + lane * 8);

        if (isP) {
            #pragma unroll
            for (int q = 0; q < 16; ++q) { acc0[q] = 0.0f; acc1[q] = 0.0f; }
            const unsigned short* bp = &bs[cur][lane * 8];
            __builtin_amdgcn_s_setprio(1);
            #pragma unroll
            for (int kc = 0; kc < 8; ++kc) {
                short8 b = *(const short8*)(bp + kc * 512);
                acc0 = __builtin_amdgcn_mfma_f32_32x32x16_bf16(af0[kc], b, acc0, 0, 0, 0);
                acc1 = __builtin_amdgcn_mfma_f32_32x32x16_bf16(af1[kc], b, acc1, 0, 0, 0);
            }
            __builtin_amdgcn_s_setprio(0);
        } else if (t > 0) {
            consume(t - 1);
        }
        __syncthreads();                       // barrier 1: C done reading acc

        // write-late staged B -> other buffer (readers done at prior barrier)
        *(short8*)(&bs[cur ^ 1][wchunk + lane * 8]) = n0;
        *(short8*)(&bs[cur ^ 1][wchunk + 512 + lane * 8]) = n1;
        if (isP) {
            // publish acc (conflict-free: lane*16B contiguous per g-KB)
            #pragma unroll
            for (int g = 0; g < 4; ++g) {
                *(f32x4*)(ab0 + g * 256 + lane * 4) =
                    (f32x4){acc0[g*4], acc0[g*4+1], acc0[g*4+2], acc0[g*4+3]};
                *(f32x4*)(ab1 + g * 256 + lane * 4) =
                    (f32x4){acc1[g*4], acc1[g*4+1], acc1[g*4+2], acc1[g*4+3]};
            }
        }
        __syncthreads();                       // barrier 2: acc(t), B(t+1) ready
    }

    if (!isP) {
        consume(63);                           // drain last tile
        // cross-column reduce, one store per output row
        #pragma unroll
        for (int q = 0; q < 16; ++q) {
            float v0 = rs0[q], v1 = rs1[q];
            v0 += __shfl_xor(v0, 1, 64);  v1 += __shfl_xor(v1, 1, 64);
            v0 += __shfl_xor(v0, 2, 64);  v1 += __shfl_xor(v1, 2, 64);
            v0 += __shfl_xor(v0, 4, 64);  v1 += __shfl_xor(v1, 4, 64);
            v0 += __shfl_xor(v0, 8, 64);  v1 += __shfl_xor(v1, 8, 64);
            v0 += __shfl_xor(v0, 16, 64); v1 += __shfl_xor(v1, 16, 64);
            if (l31 == 0) {
                const int row = (q & 3) + 8 * (q >> 2) + 4 * hi;
                partial[(long)oct * N_CLS + (long)gRow0 * 32 + row] = v0;
                partial[(long)oct * N_CLS + (long)gRow1 * 32 + row] = v1;
            }
        }
    }
}

// ---------------------------------------------------------------------------
// finalize: per row s = sum of 8 octant partials (= sum_j exp(S_ij), j!=i);
// loss = log1p(s * exp(-ap)) via u = log(s) - ap; block-sum; atomicAdd.
// ---------------------------------------------------------------------------
__global__ __launch_bounds__(256)
void finalize_kernel(const float* __restrict__ partial,
                     const float* __restrict__ ap,
                     float* __restrict__ out) {
    __shared__ float red[256];
    const int t = threadIdx.x;
    const int row = blockIdx.x * 256 + t;
    float s = 0.0f;
    #pragma unroll
    for (int p = 0; p < 8; ++p) s += partial[(long)p * N_CLS + row];
    const float u = logf(s) - ap[row];
    const float loss = (u > 25.0f) ? u : log1pf(__expf(u));
    red[t] = loss;
    __syncthreads();
    for (int st = 128; st > 0; st >>= 1) {
        if (t < st) red[t] += red[t + st];
        __syncthreads();
    }
    if (t == 0) atomicAdd(out, red[0]);
}

extern "C" void kernel_launch(void* const* d_in, const int* in_sizes, int n_in,
                              void* d_out, int out_size, void* d_ws, size_t ws_size,
                              hipStream_t stream) {
    const float* x    = (const float*)d_in[0];
    const int*   aidx = (const int*)d_in[1];
    // d_in[2] (pos_idx) derivable; unused.

    char* ws = (char*)d_ws;
    float* ap             = (float*)(ws);                                   // 64 KB
    float* partial        = (float*)(ws + 131072);                          // 512 KB (8 slots)
    unsigned short* Afrag = (unsigned short*)(ws + 131072 + 1048576);       // 4 MB
    unsigned short* Bfrag = (unsigned short*)(ws + 131072 + 1048576 + 4194304); // 4 MB

    prep_kernel<<<1024, 256, 0, stream>>>(x, aidx, ap, Afrag, Bfrag, (float*)d_out);
    fused_kernel<<<1024, 256, 0, stream>>>(Afrag, Bfrag, partial);
    finalize_kernel<<<64, 256, 0, stream>>>(partial, ap, (float*)d_out);
}

// Round 14
// 144.779 us; speedup vs baseline: 1.5137x; 1.5137x over previous
//
#include <hip/hip_runtime.h>
#include <hip/hip_bf16.h>
#include <math.h>

#define N_CLS 16384
#define DDIM  128
#define LOG2E 1.4426950408889634f

#if __has_builtin(__builtin_amdgcn_exp2f)
#define EXP2(x) __builtin_amdgcn_exp2f(x)
#else
#define EXP2(x) exp2f(x)
#endif

typedef __attribute__((ext_vector_type(8))) short short8;   // 8 bf16 (4 VGPRs)
typedef __attribute__((ext_vector_type(16))) float f32x16;  // 32x32 MFMA accumulator

__device__ __forceinline__ unsigned short f2bf(float f) {
    __hip_bfloat16 h = __float2bfloat16(f);
    return *(unsigned short*)&h;
}

// ---------------------------------------------------------------------------
// 32x32x16 fragment layout (harness-verified r1/r2/r5/r8):
//   element (rr, k) of a 32-row tile, K=128 in 8 kc chunks:
//     lane = ((k>>3)&1)*32 + (rr&31), j = k&7
//     short offset = tile*4096 + kc*512 + lane*8 + j     (tile = 8 KB)
//
// prep v4 (r8, verified): one thread per (pair i, k-slot sl), branch-free,
// fully coalesced. No CSHIFT (|S|max ~70 -> exp2 args within +-102, safe).
// ---------------------------------------------------------------------------
__global__ __launch_bounds__(256)
void prep_kernel(const float* __restrict__ x,
                 const int* __restrict__ aidx,
                 float* __restrict__ ap,
                 unsigned short* __restrict__ Afrag,
                 unsigned short* __restrict__ Bfrag,
                 float* __restrict__ out) {
    const int u  = blockIdx.x * 256 + threadIdx.x;  // unit 0..262143
    const int i  = u >> 4;                          // pair 0..16383
    const int sl = u & 15;                          // k-slot (8 floats each)
    const int k0 = sl * 8;

    const float* pa = x + (2L * i) * DDIM + k0;
    float fa[8], fb[8];
    *(float4*)&fa[0] = *(const float4*)(pa);
    *(float4*)&fa[4] = *(const float4*)(pa + 4);
    *(float4*)&fb[0] = *(const float4*)(pa + DDIM);
    *(float4*)&fb[4] = *(const float4*)(pa + DDIM + 4);
    const bool sel = (aidx[i] != 0);                // anchor = sel ? x[2i+1] : x[2i]

    short8 A, B;
    float d = 0.0f;
    #pragma unroll
    for (int j = 0; j < 8; ++j) {
        const float av = sel ? fb[j] : fa[j];
        A[j] = (short)f2bf(av * LOG2E);             // exp2 domain
        B[j] = (short)f2bf(fb[j]);                  // negative = x[2i+1]
        d += fa[j] * fb[j];                         // ap dot (symmetric)
    }
    const long dst = (long)(i >> 5) * 4096 + (sl >> 1) * 512 +
                     ((sl & 1) * 32 + (i & 31)) * 8;
    *(short8*)(Afrag + dst) = A;
    *(short8*)(Bfrag + dst) = B;

    d += __shfl_xor(d, 1, 64);
    d += __shfl_xor(d, 2, 64);
    d += __shfl_xor(d, 4, 64);
    d += __shfl_xor(d, 8, 64);
    if (sl == 0) ap[i] = d;
    if (u == 0) out[0] = 0.0f;
}

// ---------------------------------------------------------------------------
// fused v8: r2's verified R=2 structure at 3 blocks/CU.
// r13 post-mortem: wave specialization spilled (WRITE 67 MB) AND its LDS
// acc-handoff doubles LDS bytes/tile -> refuted twice. Scheduling levers
// (r5 pipelining, r8 occupancy@R=1, r11 stagger) all null. Remaining lever
// is the WORK terms: r8 spends ~21 us on LDS (R=1: 8 KB B-read per 8 MFMA)
// and r2's R=2 (2 row-tiles/wave, af0/af1) halves B-read bytes/MFMA but ran
// grid-limited at 2 blocks/CU. This round: R=2 with 1024-col groups ->
//   block = 256 rows x 1024 cols, grid = 64 x 16 = 1024 blocks = 3/CU
//   (VGPR ~151 under launch_bounds(256,3) cap 168; LDS 16 KB x3 = 48 KB).
// Per wave-step: 8 KB B-read -> 16 MFMA (R=2), 32 exp2, 1 barrier.
// colgrp = bid&15 (XCD = bid&7: two 256 KB B slices per XCD L2). 16 partial
// slots (1 MB, fits existing ws gap). WRITE_SIZE ~1 MB now is EXPECTED
// (16 slots); spill signature is >> 1 MB.
// ---------------------------------------------------------------------------
__global__ __launch_bounds__(256, 3)
void fused_kernel(const unsigned short* __restrict__ Afrag,
                  const unsigned short* __restrict__ Bfrag,
                  float* __restrict__ partial) {
    __shared__ __align__(16) unsigned short bs[2][4096];   // 2 x 8 KB
    const int tid  = threadIdx.x;
    const int lane = tid & 63;
    const int w    = tid >> 6;                 // wave 0..3
    const int l31  = lane & 31;
    const int hi   = lane >> 5;
    const int cg   = blockIdx.x & 15;          // 1024-col group (XCD = bid&7)
    const int rt   = blockIdx.x >> 4;          // 0..63 (256-row block)
    const int r0   = rt * 8 + w * 2;           // this wave's 32-row tiles
    const int r1   = r0 + 1;

    // hoist A: two 32-row tiles, all 8 kc (64 VGPRs)
    short8 af0[8], af1[8];
    {
        const unsigned short* a0 = Afrag + (long)r0 * 4096 + lane * 8;
        const unsigned short* a1 = Afrag + (long)r1 * 4096 + lane * 8;
        #pragma unroll
        for (int kc = 0; kc < 8; ++kc) {
            af0[kc] = *(const short8*)(a0 + kc * 512);
            af1[kc] = *(const short8*)(a1 + kc * 512);
        }
    }
    const unsigned short* bbase = Bfrag + (long)cg * (32L * 4096) + lane * 8;
    const int wchunk = w * 1024;               // this wave's 2 stage chunks

    // diagonal col-tiles (wave-uniform; sentinel outside 0..31)
    int ctd0 = r0 - cg * 32;
    int ctd1 = r1 - cg * 32;
    if (ctd0 < 0 || ctd0 >= 32) ctd0 = -1000;
    if (ctd1 < 0 || ctd1 >= 32) ctd1 = -1000;

    float rs0[16], rs1[16];
    #pragma unroll
    for (int q = 0; q < 16; ++q) { rs0[q] = 0.0f; rs1[q] = 0.0f; }

    // prologue: stage tile 0 into bs[0]
    {
        short8 s0 = *(const short8*)(bbase + wchunk);
        short8 s1 = *(const short8*)(bbase + wchunk + 512);
        *(short8*)(&bs[0][wchunk + lane * 8]) = s0;
        *(short8*)(&bs[0][wchunk + 512 + lane * 8]) = s1;
    }
    __syncthreads();

    for (int ct = 0; ct < 32; ++ct) {
        const int cur = ct & 1;
        // issue next-tile loads early; tile 31 harmlessly reloads itself
        const long nt = (ct < 31) ? (long)(ct + 1) : 31L;
        short8 n0 = *(const short8*)(bbase + nt * 4096 + wchunk);
        short8 n1 = *(const short8*)(bbase + nt * 4096 + wchunk + 512);

        f32x16 acc0, acc1;
        #pragma unroll
        for (int q = 0; q < 16; ++q) { acc0[q] = 0.0f; acc1[q] = 0.0f; }

        const unsigned short* bp = &bs[cur][lane * 8];
        __builtin_amdgcn_s_setprio(1);
        #pragma unroll
        for (int kc = 0; kc < 8; ++kc) {
            short8 b = *(const short8*)(bp + kc * 512);
            acc0 = __builtin_amdgcn_mfma_f32_32x32x16_bf16(af0[kc], b, acc0, 0, 0, 0);
            acc1 = __builtin_amdgcn_mfma_f32_32x32x16_bf16(af1[kc], b, acc1, 0, 0, 0);
        }
        __builtin_amdgcn_s_setprio(0);

        if (ct == ctd0) {
            #pragma unroll
            for (int q = 0; q < 16; ++q) {
                const float e = EXP2(acc0[q]);
                const int row = (q & 3) + 8 * (q >> 2) + 4 * hi;  // C/D row map
                rs0[q] += (l31 == row) ? 0.0f : e;
            }
        } else {
            #pragma unroll
            for (int q = 0; q < 16; ++q) rs0[q] += EXP2(acc0[q]);
        }
        if (ct == ctd1) {
            #pragma unroll
            for (int q = 0; q < 16; ++q) {
                const float e = EXP2(acc1[q]);
                const int row = (q & 3) + 8 * (q >> 2) + 4 * hi;
                rs1[q] += (l31 == row) ? 0.0f : e;
            }
        } else {
            #pragma unroll
            for (int q = 0; q < 16; ++q) rs1[q] += EXP2(acc1[q]);
        }

        // write-late: staged tile -> other buffer (its readers finished at
        // the barrier ending iteration ct-1)
        *(short8*)(&bs[cur ^ 1][wchunk + lane * 8]) = n0;
        *(short8*)(&bs[cur ^ 1][wchunk + 512 + lane * 8]) = n1;
        __syncthreads();
    }

    // cross-column reduce (l31 bits via xor 1..16), one store per output row
    #pragma unroll
    for (int q = 0; q < 16; ++q) {
        float v0 = rs0[q], v1 = rs1[q];
        v0 += __shfl_xor(v0, 1, 64);  v1 += __shfl_xor(v1, 1, 64);
        v0 += __shfl_xor(v0, 2, 64);  v1 += __shfl_xor(v1, 2, 64);
        v0 += __shfl_xor(v0, 4, 64);  v1 += __shfl_xor(v1, 4, 64);
        v0 += __shfl_xor(v0, 8, 64);  v1 += __shfl_xor(v1, 8, 64);
        v0 += __shfl_xor(v0, 16, 64); v1 += __shfl_xor(v1, 16, 64);
        if (l31 == 0) {
            const int row = (q & 3) + 8 * (q >> 2) + 4 * hi;
            partial[(long)cg * N_CLS + (long)r0 * 32 + row] = v0;
            partial[(long)cg * N_CLS + (long)r1 * 32 + row] = v1;
        }
    }
}

// ---------------------------------------------------------------------------
// finalize: per row s = sum of 16 col-group partials (= sum_j exp(S_ij), j!=i);
// loss = log1p(s * exp(-ap)) via u = log(s) - ap; block-sum; atomicAdd.
// ---------------------------------------------------------------------------
__global__ __launch_bounds__(256)
void finalize_kernel(const float* __restrict__ partial,
                     const float* __restrict__ ap,
                     float* __restrict__ out) {
    __shared__ float red[256];
    const int t = threadIdx.x;
    const int row = blockIdx.x * 256 + t;
    float s = 0.0f;
    #pragma unroll
    for (int p = 0; p < 16; ++p) s += partial[(long)p * N_CLS + row];
    const float u = logf(s) - ap[row];
    const float loss = (u > 25.0f) ? u : log1pf(__expf(u));
    red[t] = loss;
    __syncthreads();
    for (int st = 128; st > 0; st >>= 1) {
        if (t < st) red[t] += red[t + st];
        __syncthreads();
    }
    if (t == 0) atomicAdd(out, red[0]);
}

extern "C" void kernel_launch(void* const* d_in, const int* in_sizes, int n_in,
                              void* d_out, int out_size, void* d_ws, size_t ws_size,
                              hipStream_t stream) {
    const float* x    = (const float*)d_in[0];
    const int*   aidx = (const int*)d_in[1];
    // d_in[2] (pos_idx) derivable; unused.

    char* ws = (char*)d_ws;
    float* ap             = (float*)(ws);                                   // 64 KB
    float* partial        = (float*)(ws + 131072);                          // 1 MB (16 slots)
    unsigned short* Afrag = (unsigned short*)(ws + 131072 + 1048576);       // 4 MB
    unsigned short* Bfrag = (unsigned short*)(ws + 131072 + 1048576 + 4194304); // 4 MB

    prep_kernel<<<1024, 256, 0, stream>>>(x, aidx, ap, Afrag, Bfrag, (float*)d_out);
    fused_kernel<<<1024, 256, 0, stream>>>(Afrag, Bfrag, partial);
    finalize_kernel<<<64, 256, 0, stream>>>(partial, ap, (float*)d_out);
}

// Round 15
// 144.454 us; speedup vs baseline: 1.5171x; 1.0023x over previous
//
#include <hip/hip_runtime.h>
#include <hip/hip_bf16.h>
#include <math.h>

#define N_CLS 16384
#define DDIM  128
#define LOG2E 1.4426950408889634f

#if __has_builtin(__builtin_amdgcn_exp2f)
#define EXP2(x) __builtin_amdgcn_exp2f(x)
#else
#define EXP2(x) exp2f(x)
#endif

typedef __attribute__((ext_vector_type(8))) short short8;   // 8 bf16 (4 VGPRs)
typedef __attribute__((ext_vector_type(16))) float f32x16;  // 32x32 MFMA accumulator

__device__ __forceinline__ unsigned short f2bf(float f) {
    __hip_bfloat16 h = __float2bfloat16(f);
    return *(unsigned short*)&h;
}

// ---------------------------------------------------------------------------
// 32x32x16 fragment layout (harness-verified r1/r2/r5/r8/r14):
//   element (rr, k) of a 32-row tile, K=128 in 8 kc chunks:
//     lane = ((k>>3)&1)*32 + (rr&31), j = k&7
//     short offset = tile*4096 + kc*512 + lane*8 + j     (tile = 8 KB)
//
// prep v4 (r8, verified): one thread per (pair i, k-slot sl), branch-free,
// fully coalesced. No CSHIFT (|S|max ~70 -> exp2 args within +-102, safe).
// ---------------------------------------------------------------------------
__global__ __launch_bounds__(256)
void prep_kernel(const float* __restrict__ x,
                 const int* __restrict__ aidx,
                 float* __restrict__ ap,
                 unsigned short* __restrict__ Afrag,
                 unsigned short* __restrict__ Bfrag,
                 float* __restrict__ out) {
    const int u  = blockIdx.x * 256 + threadIdx.x;  // unit 0..262143
    const int i  = u >> 4;                          // pair 0..16383
    const int sl = u & 15;                          // k-slot (8 floats each)
    const int k0 = sl * 8;

    const float* pa = x + (2L * i) * DDIM + k0;
    float fa[8], fb[8];
    *(float4*)&fa[0] = *(const float4*)(pa);
    *(float4*)&fa[4] = *(const float4*)(pa + 4);
    *(float4*)&fb[0] = *(const float4*)(pa + DDIM);
    *(float4*)&fb[4] = *(const float4*)(pa + DDIM + 4);
    const bool sel = (aidx[i] != 0);                // anchor = sel ? x[2i+1] : x[2i]

    short8 A, B;
    float d = 0.0f;
    #pragma unroll
    for (int j = 0; j < 8; ++j) {
        const float av = sel ? fb[j] : fa[j];
        A[j] = (short)f2bf(av * LOG2E);             // exp2 domain
        B[j] = (short)f2bf(fb[j]);                  // negative = x[2i+1]
        d += fa[j] * fb[j];                         // ap dot (symmetric)
    }
    const long dst = (long)(i >> 5) * 4096 + (sl >> 1) * 512 +
                     ((sl & 1) * 32 + (i & 31)) * 8;
    *(short8*)(Afrag + dst) = A;
    *(short8*)(Bfrag + dst) = B;

    d += __shfl_xor(d, 1, 64);
    d += __shfl_xor(d, 2, 64);
    d += __shfl_xor(d, 4, 64);
    d += __shfl_xor(d, 8, 64);
    if (sl == 0) ap[i] = d;
    if (u == 0) out[0] = 0.0f;
}

// ---------------------------------------------------------------------------
// fused v9: BARRIER-FREE (r0's structure) + 32x32 R=2 + L1-broadcast B.
// Cross-round invariant (r1/r2/r8/r14): MFMA-busy ~29-30 us and VALU-busy
// ~25-27 us are CONSTANT; only dead time varies (r8 19us barrier drains,
// r1 36us uncovered L2 latency on a 256-cyc single chain, r14 30us).
// All overlap levers measured null -> wall = 30 + 26 + dead. Attack dead:
//  - NO LDS, NO barriers (r0, the best at 73.2, is the only barrier-free
//    kernel). B comes straight from L2 via L1: all 4 waves of a block read
//    the SAME B-tile addresses -> L1 broadcasts x4 (this is why r1 wasn't
//    L2-throughput-bound).
//  - R=2 dual chains: 16 MFMA x 32cyc = 512 cyc/tile covers the ~300cyc
//    L2 latency of the next tile's 8 prefetch loads (fixes r1's stall).
//  - bP/bQ two-bank prefetch, statically 2x-unrolled (r0's pattern).
//  - acc zero-init via C-operand (zacc), no per-tile v_movs.
// block = 256 rows x 1024 cols; wave = 2x 32-row tiles x 32 col-tiles.
// grid = 64 rg x 16 cg = 1024 blocks (cg = bid&15, XCD = bid&7).
// VGPR ~220 (af 64 + acc 32 + rs 32 + bP/bQ 64 + misc) -> (256,2).
// Spill signature: WRITE_SIZE >> 1 MB. Falsifier: >=73 us -> structural
// ceiling; restore best-known config and stop.
// ---------------------------------------------------------------------------
__global__ __launch_bounds__(256, 2)
void fused_kernel(const unsigned short* __restrict__ Afrag,
                  const unsigned short* __restrict__ Bfrag,
                  float* __restrict__ partial) {
    const int tid  = threadIdx.x;
    const int lane = tid & 63;
    const int w    = tid >> 6;                 // wave 0..3
    const int l31  = lane & 31;
    const int hi   = lane >> 5;
    const int cg   = blockIdx.x & 15;          // 1024-col group (XCD = bid&7)
    const int rg   = blockIdx.x >> 4;          // 0..63 (256-row block)
    const int r0   = rg * 8 + w * 2;           // this wave's 32-row tiles
    const int r1   = r0 + 1;

    // hoist A: two 32-row tiles, all 8 kc (64 VGPRs)
    short8 af0[8], af1[8];
    {
        const unsigned short* a0 = Afrag + (long)r0 * 4096 + lane * 8;
        const unsigned short* a1 = Afrag + (long)r1 * 4096 + lane * 8;
        #pragma unroll
        for (int kc = 0; kc < 8; ++kc) {
            af0[kc] = *(const short8*)(a0 + kc * 512);
            af1[kc] = *(const short8*)(a1 + kc * 512);
        }
    }
    // all 4 waves share this address stream -> L1 broadcast
    const unsigned short* bbase = Bfrag + (long)(cg * 32) * 4096 + lane * 8;

    // diagonal col-tiles (wave-uniform; sentinel outside 0..31)
    int ctd0 = r0 - cg * 32;
    int ctd1 = r1 - cg * 32;
    if (ctd0 < 0 || ctd0 >= 32) ctd0 = -1000;
    if (ctd1 < 0 || ctd1 >= 32) ctd1 = -1000;

    float rs0[16], rs1[16];
    #pragma unroll
    for (int q = 0; q < 16; ++q) { rs0[q] = 0.0f; rs1[q] = 0.0f; }

    const f32x16 zacc = {0.0f, 0.0f, 0.0f, 0.0f, 0.0f, 0.0f, 0.0f, 0.0f,
                         0.0f, 0.0f, 0.0f, 0.0f, 0.0f, 0.0f, 0.0f, 0.0f};
    short8 bP[8], bQ[8];

    auto compute_epi = [&](short8 (&bk)[8], int ct) {
        f32x16 acc0, acc1;
        __builtin_amdgcn_s_setprio(1);
        #pragma unroll
        for (int kc = 0; kc < 8; ++kc) {
            acc0 = __builtin_amdgcn_mfma_f32_32x32x16_bf16(
                       af0[kc], bk[kc], (kc == 0) ? zacc : acc0, 0, 0, 0);
            acc1 = __builtin_amdgcn_mfma_f32_32x32x16_bf16(
                       af1[kc], bk[kc], (kc == 0) ? zacc : acc1, 0, 0, 0);
        }
        __builtin_amdgcn_s_setprio(0);
        if (ct == ctd0) {
            #pragma unroll
            for (int q = 0; q < 16; ++q) {
                const float e = EXP2(acc0[q]);
                const int row = (q & 3) + 8 * (q >> 2) + 4 * hi;  // C/D row map
                rs0[q] += (l31 == row) ? 0.0f : e;
            }
        } else {
            #pragma unroll
            for (int q = 0; q < 16; ++q) rs0[q] += EXP2(acc0[q]);
        }
        if (ct == ctd1) {
            #pragma unroll
            for (int q = 0; q < 16; ++q) {
                const float e = EXP2(acc1[q]);
                const int row = (q & 3) + 8 * (q >> 2) + 4 * hi;
                rs1[q] += (l31 == row) ? 0.0f : e;
            }
        } else {
            #pragma unroll
            for (int q = 0; q < 16; ++q) rs1[q] += EXP2(acc1[q]);
        }
    };

    // prologue: load tile 0 into bP
    #pragma unroll
    for (int kc = 0; kc < 8; ++kc)
        bP[kc] = *(const short8*)(bbase + kc * 512);

    for (int ct = 0; ct < 32; ct += 2) {
        // prefetch tile ct+1 into bQ (issued before the MFMA chain; its
        // ~300cyc L2/L1 latency hides under the 512cyc dual chain + exp)
        const unsigned short* p1 = bbase + (long)(ct + 1) * 4096;
        #pragma unroll
        for (int kc = 0; kc < 8; ++kc)
            bQ[kc] = *(const short8*)(p1 + kc * 512);
        compute_epi(bP, ct);

        // prefetch tile ct+2 into bP (ct=30 -> harmless self-reload of 31)
        const unsigned short* p2 = bbase + (long)((ct < 30) ? ct + 2 : 31) * 4096;
        #pragma unroll
        for (int kc = 0; kc < 8; ++kc)
            bP[kc] = *(const short8*)(p2 + kc * 512);
        compute_epi(bQ, ct + 1);
    }

    // cross-column reduce (l31 bits via xor 1..16), one store per output row
    #pragma unroll
    for (int q = 0; q < 16; ++q) {
        float v0 = rs0[q], v1 = rs1[q];
        v0 += __shfl_xor(v0, 1, 64);  v1 += __shfl_xor(v1, 1, 64);
        v0 += __shfl_xor(v0, 2, 64);  v1 += __shfl_xor(v1, 2, 64);
        v0 += __shfl_xor(v0, 4, 64);  v1 += __shfl_xor(v1, 4, 64);
        v0 += __shfl_xor(v0, 8, 64);  v1 += __shfl_xor(v1, 8, 64);
        v0 += __shfl_xor(v0, 16, 64); v1 += __shfl_xor(v1, 16, 64);
        if (l31 == 0) {
            const int row = (q & 3) + 8 * (q >> 2) + 4 * hi;
            partial[(long)cg * N_CLS + (long)r0 * 32 + row] = v0;
            partial[(long)cg * N_CLS + (long)r1 * 32 + row] = v1;
        }
    }
}

// ---------------------------------------------------------------------------
// finalize: per row s = sum of 16 col-group partials (= sum_j exp(S_ij), j!=i);
// loss = log1p(s * exp(-ap)) via u = log(s) - ap; block-sum; atomicAdd.
// ---------------------------------------------------------------------------
__global__ __launch_bounds__(256)
void finalize_kernel(const float* __restrict__ partial,
                     const float* __restrict__ ap,
                     float* __restrict__ out) {
    __shared__ float red[256];
    const int t = threadIdx.x;
    const int row = blockIdx.x * 256 + t;
    float s = 0.0f;
    #pragma unroll
    for (int p = 0; p < 16; ++p) s += partial[(long)p * N_CLS + row];
    const float u = logf(s) - ap[row];
    const float loss = (u > 25.0f) ? u : log1pf(__expf(u));
    red[t] = loss;
    __syncthreads();
    for (int st = 128; st > 0; st >>= 1) {
        if (t < st) red[t] += red[t + st];
        __syncthreads();
    }
    if (t == 0) atomicAdd(out, red[0]);
}

extern "C" void kernel_launch(void* const* d_in, const int* in_sizes, int n_in,
                              void* d_out, int out_size, void* d_ws, size_t ws_size,
                              hipStream_t stream) {
    const float* x    = (const float*)d_in[0];
    const int*   aidx = (const int*)d_in[1];
    // d_in[2] (pos_idx) derivable; unused.

    char* ws = (char*)d_ws;
    float* ap             = (float*)(ws);                                   // 64 KB
    float* partial        = (float*)(ws + 131072);                          // 1 MB (16 slots)
    unsigned short* Afrag = (unsigned short*)(ws + 131072 + 1048576);       // 4 MB
    unsigned short* Bfrag = (unsigned short*)(ws + 131072 + 1048576 + 4194304); // 4 MB

    prep_kernel<<<1024, 256, 0, stream>>>(x, aidx, ap, Afrag, Bfrag, (float*)d_out);
    fused_kernel<<<1024, 256, 0, stream>>>(Afrag, Bfrag, partial);
    finalize_kernel<<<64, 256, 0, stream>>>(partial, ap, (float*)d_out);
}